// Round 9
// baseline (489.141 us; speedup 1.0000x reference)
//
#include <hip/hip_runtime.h>

#define N_TOT 50500
#define E_NUM 800000
#define D_IN_ 100
#define D_HID 200
#define ALPHA 0.2f
#define EPS_ 1e-12f
#define SCAN_B 256
#define NBLK_SCAN ((N_TOT + SCAN_B - 1) / SCAN_B)  // 198
#define LDPA 132  // A row-dim pad: 132*4 = 528 B (16B-aligned rows)
#define LDPB 68   // B col-dim pad: 68*4 = 272 B

// ---------------------------------------------------------------------------
// fp32 GEMM: C[N,M] = A[N,K] @ B[K,M]. 128(rows)x64(cols) tile, BK=16,
// 256 threads, 8x4 microtile. Per kk: 2 b128 A-reads (16-lane broadcast,
// conflict-free) + 1 b128 B-read (2-way, free) feed 32 FMAs -> FMA-bound.
// Grid (M/64, N/128) = 1580 blocks keeps ~25 waves/CU (R7's 128x128 tile
// dropped to 3.1 blocks/CU and stalled at 19% occupancy).
// ---------------------------------------------------------------------------
__global__ __launch_bounds__(256) void dummy_anchor() {}  // keep name-space tidy

template <bool LRELU>
__global__ __launch_bounds__(256) void gemm_kernel(
    const float* __restrict__ A, const float* __restrict__ B,
    float* __restrict__ C, int Nn, int K, int M) {
  __shared__ float As[16][LDPA];  // [k][row 0..127]
  __shared__ float Bs[16][LDPB];  // [k][col 0..63]
  const int tid = threadIdx.x;
  const int tx = tid & 15;   // col group: cols tx*4..+3
  const int ty = tid >> 4;   // row group: rows ty*8..+7
  const int colBase = blockIdx.x * 64;
  const int rowBase = blockIdx.y * 128;

  // staging coords
  const int sar = tid >> 1;        // A: row 0..127
  const int sak = (tid & 1) * 8;   // A: k offset 0 or 8 (two float4s)
  const int sbk = tid >> 4;        // B: k 0..15
  const int sbc = (tid & 15) * 4;  // B: col 0..60

  float acc[8][4] = {};

  for (int k0 = 0; k0 < K; k0 += 16) {
    // ---- stage A: 128 rows x 16 k; 2 float4s per thread ----
    {
      int gr = rowBase + sar;
      const float* Ar = A + (long)gr * K;
#pragma unroll
      for (int h = 0; h < 2; ++h) {
        int gk = k0 + sak + h * 4;
        float4 v = {0.f, 0.f, 0.f, 0.f};
        if (gr < Nn) {
          if (gk + 3 < K) {
            v = *reinterpret_cast<const float4*>(Ar + gk);
          } else {
            v.x = (gk + 0 < K) ? Ar[gk + 0] : 0.f;
            v.y = (gk + 1 < K) ? Ar[gk + 1] : 0.f;
            v.z = (gk + 2 < K) ? Ar[gk + 2] : 0.f;
            v.w = (gk + 3 < K) ? Ar[gk + 3] : 0.f;
          }
        }
        As[sak + h * 4 + 0][sar] = v.x;
        As[sak + h * 4 + 1][sar] = v.y;
        As[sak + h * 4 + 2][sar] = v.z;
        As[sak + h * 4 + 3][sar] = v.w;
      }
    }
    // ---- stage B: 16 k x 64 cols; 1 float4 per thread ----
    {
      float4 v = {0.f, 0.f, 0.f, 0.f};
      int gk = k0 + sbk;
      int gc = colBase + sbc;
      if (gk < K) {
        if (gc + 3 < M) {
          v = *reinterpret_cast<const float4*>(B + (long)gk * M + gc);
        } else {
          v.x = (gc + 0 < M) ? B[(long)gk * M + gc + 0] : 0.f;
          v.y = (gc + 1 < M) ? B[(long)gk * M + gc + 1] : 0.f;
          v.z = (gc + 2 < M) ? B[(long)gk * M + gc + 2] : 0.f;
          v.w = (gc + 3 < M) ? B[(long)gk * M + gc + 3] : 0.f;
        }
      }
      *reinterpret_cast<float4*>(&Bs[sbk][sbc]) = v;
    }
    __syncthreads();

#pragma unroll
    for (int kk = 0; kk < 16; ++kk) {
      float4 a0 = *reinterpret_cast<const float4*>(&As[kk][ty * 8]);
      float4 a1 = *reinterpret_cast<const float4*>(&As[kk][ty * 8 + 4]);
      float4 b = *reinterpret_cast<const float4*>(&Bs[kk][tx * 4]);
      acc[0][0] += a0.x * b.x; acc[0][1] += a0.x * b.y;
      acc[0][2] += a0.x * b.z; acc[0][3] += a0.x * b.w;
      acc[1][0] += a0.y * b.x; acc[1][1] += a0.y * b.y;
      acc[1][2] += a0.y * b.z; acc[1][3] += a0.y * b.w;
      acc[2][0] += a0.z * b.x; acc[2][1] += a0.z * b.y;
      acc[2][2] += a0.z * b.z; acc[2][3] += a0.z * b.w;
      acc[3][0] += a0.w * b.x; acc[3][1] += a0.w * b.y;
      acc[3][2] += a0.w * b.z; acc[3][3] += a0.w * b.w;
      acc[4][0] += a1.x * b.x; acc[4][1] += a1.x * b.y;
      acc[4][2] += a1.x * b.z; acc[4][3] += a1.x * b.w;
      acc[5][0] += a1.y * b.x; acc[5][1] += a1.y * b.y;
      acc[5][2] += a1.y * b.z; acc[5][3] += a1.y * b.w;
      acc[6][0] += a1.z * b.x; acc[6][1] += a1.z * b.y;
      acc[6][2] += a1.z * b.z; acc[6][3] += a1.z * b.w;
      acc[7][0] += a1.w * b.x; acc[7][1] += a1.w * b.y;
      acc[7][2] += a1.w * b.z; acc[7][3] += a1.w * b.w;
    }
    __syncthreads();
  }

  // ---- write C: 8 rows x one float4 (M % 4 == 0) ----
  const int gc = colBase + tx * 4;
  if (gc + 3 < M) {
#pragma unroll
    for (int i = 0; i < 8; ++i) {
      int gr = rowBase + ty * 8 + i;
      if (gr < Nn) {
        float4 o = {acc[i][0], acc[i][1], acc[i][2], acc[i][3]};
        if (LRELU) {
          o.x = o.x > 0.f ? o.x : ALPHA * o.x;
          o.y = o.y > 0.f ? o.y : ALPHA * o.y;
          o.z = o.z > 0.f ? o.z : ALPHA * o.z;
          o.w = o.w > 0.f ? o.w : ALPHA * o.w;
        }
        *reinterpret_cast<float4*>(C + (long)gr * M + gc) = o;
      }
    }
  }
}

// ---------------------------------------------------------------------------
// CSR build: histogram -> 3-kernel exclusive scan -> fill. (unchanged)
// ---------------------------------------------------------------------------
__global__ __launch_bounds__(256) void hist_kernel(const int* __restrict__ dst,
                                                   int* __restrict__ counts) {
  int e = blockIdx.x * blockDim.x + threadIdx.x;
  if (e < E_NUM) atomicAdd(&counts[dst[e]], 1);
}

__global__ __launch_bounds__(SCAN_B) void scan1_kernel(
    const int* __restrict__ counts, int* __restrict__ starts,
    int* __restrict__ blockSums) {
  __shared__ int s[SCAN_B];
  int i = blockIdx.x * SCAN_B + threadIdx.x;
  int v = (i < N_TOT) ? counts[i] : 0;
  s[threadIdx.x] = v;
  __syncthreads();
  for (int off = 1; off < SCAN_B; off <<= 1) {
    int t = (threadIdx.x >= off) ? s[threadIdx.x - off] : 0;
    __syncthreads();
    s[threadIdx.x] += t;
    __syncthreads();
  }
  if (i < N_TOT) starts[i] = s[threadIdx.x] - v;
  if (threadIdx.x == SCAN_B - 1) blockSums[blockIdx.x] = s[threadIdx.x];
}

__global__ __launch_bounds__(SCAN_B) void scan2_kernel(
    int* __restrict__ blockSums) {
  __shared__ int s[SCAN_B];
  int v = (threadIdx.x < NBLK_SCAN) ? blockSums[threadIdx.x] : 0;
  s[threadIdx.x] = v;
  __syncthreads();
  for (int off = 1; off < SCAN_B; off <<= 1) {
    int t = (threadIdx.x >= off) ? s[threadIdx.x - off] : 0;
    __syncthreads();
    s[threadIdx.x] += t;
    __syncthreads();
  }
  if (threadIdx.x < NBLK_SCAN) blockSums[threadIdx.x] = s[threadIdx.x] - v;
}

__global__ __launch_bounds__(SCAN_B) void scan3_kernel(
    int* __restrict__ starts, const int* __restrict__ blockSums,
    int* __restrict__ cursor) {
  int i = blockIdx.x * SCAN_B + threadIdx.x;
  if (i < N_TOT) {
    int st = starts[i] + blockSums[blockIdx.x];
    starts[i] = st;
    cursor[i] = st;
  }
}

__global__ __launch_bounds__(256) void fill_kernel(
    const int* __restrict__ src, const int* __restrict__ dst,
    const float* __restrict__ vals, int* __restrict__ cursor,
    int* __restrict__ csrSrc, float* __restrict__ csrVal) {
  int e = blockIdx.x * blockDim.x + threadIdx.x;
  if (e >= E_NUM) return;
  int d = dst[e];
  int pos = atomicAdd(&cursor[d], 1);
  csrSrc[pos] = src[e];
  csrVal[pos] = vals[e];
}

// ---------------------------------------------------------------------------
// Pure pull aggregation, one wave per row, 4x unroll. (unchanged from R7)
// ---------------------------------------------------------------------------
template <int CHUNKS>
__global__ __launch_bounds__(256) void agg_kernel(
    const float* __restrict__ h, const int* __restrict__ starts,
    const int* __restrict__ counts, const int* __restrict__ csrSrc,
    const float* __restrict__ csrVal, float* __restrict__ out) {
  const int wave = threadIdx.x >> 6;
  const int lane = threadIdx.x & 63;
  const int row = blockIdx.x * 4 + wave;
  if (row >= N_TOT) return;
  const int st = starts[row];
  const int cnt = counts[row];
  const float4* __restrict__ h4 = reinterpret_cast<const float4*>(h);

  float4 acc = {0.f, 0.f, 0.f, 0.f};
  int j = 0;
  for (; j + 3 < cnt; j += 4) {
    int s0 = csrSrc[st + j + 0], s1 = csrSrc[st + j + 1];
    int s2 = csrSrc[st + j + 2], s3 = csrSrc[st + j + 3];
    float v0 = csrVal[st + j + 0], v1 = csrVal[st + j + 1];
    float v2 = csrVal[st + j + 2], v3 = csrVal[st + j + 3];
    if (lane < CHUNKS) {
      float4 a = h4[(long)s0 * CHUNKS + lane];
      float4 b = h4[(long)s1 * CHUNKS + lane];
      float4 c = h4[(long)s2 * CHUNKS + lane];
      float4 d = h4[(long)s3 * CHUNKS + lane];
      acc.x += a.x * v0 + b.x * v1 + c.x * v2 + d.x * v3;
      acc.y += a.y * v0 + b.y * v1 + c.y * v2 + d.y * v3;
      acc.z += a.z * v0 + b.z * v1 + c.z * v2 + d.z * v3;
      acc.w += a.w * v0 + b.w * v1 + c.w * v2 + d.w * v3;
    }
  }
  for (; j < cnt; ++j) {
    int s0 = csrSrc[st + j];
    float v0 = csrVal[st + j];
    if (lane < CHUNKS) {
      float4 a = h4[(long)s0 * CHUNKS + lane];
      acc.x += a.x * v0;
      acc.y += a.y * v0;
      acc.z += a.z * v0;
      acc.w += a.w * v0;
    }
  }
  if (lane < CHUNKS)
    reinterpret_cast<float4*>(out)[(long)row * CHUNKS + lane] = acc;
}

// ---------------------------------------------------------------------------
// Fused LeakyReLU + L2 row-normalize, in place. (unchanged)
// ---------------------------------------------------------------------------
__global__ __launch_bounds__(256) void norm_kernel(float* __restrict__ x) {
  const int wave = threadIdx.x >> 6;
  const int lane = threadIdx.x & 63;
  const int row = blockIdx.x * 4 + wave;
  if (row >= N_TOT) return;
  float* p = x + (long)row * D_HID;
  float4 v = {0.f, 0.f, 0.f, 0.f};
  if (lane < 50) {
    v = *reinterpret_cast<float4*>(p + lane * 4);
    v.x = v.x > 0.f ? v.x : ALPHA * v.x;
    v.y = v.y > 0.f ? v.y : ALPHA * v.y;
    v.z = v.z > 0.f ? v.z : ALPHA * v.z;
    v.w = v.w > 0.f ? v.w : ALPHA * v.w;
  }
  float ss = v.x * v.x + v.y * v.y + v.z * v.z + v.w * v.w;
#pragma unroll
  for (int off = 32; off; off >>= 1) ss += __shfl_xor(ss, off);
  float inv = 1.f / fmaxf(sqrtf(ss), EPS_);
  if (lane < 50) {
    float4 o = {v.x * inv, v.y * inv, v.z * inv, v.w * inv};
    *reinterpret_cast<float4*>(p + lane * 4) = o;
  }
}

// ---------------------------------------------------------------------------
extern "C" void kernel_launch(void* const* d_in, const int* in_sizes, int n_in,
                              void* d_out, int out_size, void* d_ws,
                              size_t ws_size, hipStream_t stream) {
  const float* emb = (const float*)d_in[0];   // [N_TOT, 100]
  const float* W1 = (const float*)d_in[1];    // [100, 200]
  const float* W2 = (const float*)d_in[2];    // [200, 200]
  const int* eidx = (const int*)d_in[3];      // [2, E]
  const float* vals = (const float*)d_in[4];  // [E]
  const int* src = eidx;
  const int* dst = eidx + E_NUM;
  float* out = (float*)d_out;                 // [N_TOT, 200] flat

  // ---- workspace layout (~68 MB) ----
  char* p = (char*)d_ws;
  auto take = [&](size_t bytes) {
    char* r = p;
    p += (bytes + 255) & ~(size_t)255;
    return r;
  };
  float* g1 = (float*)take((size_t)N_TOT * D_IN_ * sizeof(float));   // 20.2 MB
  float* g2 = (float*)take((size_t)N_TOT * D_HID * sizeof(float));   // 40.4 MB
  int* csrSrc = (int*)take((size_t)E_NUM * sizeof(int));
  float* csrVal = (float*)take((size_t)E_NUM * sizeof(float));
  int* counts = (int*)take((size_t)N_TOT * sizeof(int));
  int* starts = (int*)take((size_t)N_TOT * sizeof(int));
  int* cursor = (int*)take((size_t)N_TOT * sizeof(int));
  int* blockSums = (int*)take((size_t)NBLK_SCAN * sizeof(int));

  const int eBlocks = (E_NUM + 255) / 256;
  const int rowWaveBlocks = (N_TOT + 3) / 4;

  // ---- CSR build (once; shared by both layers) ----
  hipMemsetAsync(counts, 0, (size_t)N_TOT * sizeof(int), stream);
  hist_kernel<<<eBlocks, 256, 0, stream>>>(dst, counts);
  scan1_kernel<<<NBLK_SCAN, SCAN_B, 0, stream>>>(counts, starts, blockSums);
  scan2_kernel<<<1, SCAN_B, 0, stream>>>(blockSums);
  scan3_kernel<<<NBLK_SCAN, SCAN_B, 0, stream>>>(starts, blockSums, cursor);
  fill_kernel<<<eBlocks, 256, 0, stream>>>(src, dst, vals, cursor, csrSrc,
                                           csrVal);

  dim3 gemmGrid((D_HID + 63) / 64, (N_TOT + 127) / 128);  // (4, 395)

  // ---- layer 1: aggregate emb in 100-dim, then project (+lrelu) ----
  agg_kernel<25><<<rowWaveBlocks, 256, 0, stream>>>(emb, starts, counts,
                                                    csrSrc, csrVal, g1);
  gemm_kernel<true><<<gemmGrid, 256, 0, stream>>>(g1, W1, out /*h1*/, N_TOT,
                                                  D_IN_, D_HID);

  // ---- layer 2: aggregate h1, project, then lrelu+normalize ----
  agg_kernel<50><<<rowWaveBlocks, 256, 0, stream>>>(out, starts, counts,
                                                    csrSrc, csrVal, g2);
  gemm_kernel<false><<<gemmGrid, 256, 0, stream>>>(g2, W2, out, N_TOT, D_HID,
                                                   D_HID);
  norm_kernel<<<rowWaveBlocks, 256, 0, stream>>>(out);
}

// Round 12
// 481.908 us; speedup vs baseline: 1.0150x; 1.0150x over previous
//
#include <hip/hip_runtime.h>

#define N_TOT 50500
#define E_NUM 800000
#define D_IN_ 100
#define D_HID 200
#define ALPHA 0.2f
#define EPS_ 1e-12f
#define SCAN_B 256
#define NBLK_SCAN ((N_TOT + SCAN_B - 1) / SCAN_B)  // 198
#define LDPA 132  // A row-dim pad: 132*4 = 528 B (16B-aligned rows)
#define LDPB 68   // B col-dim pad: 68*4 = 272 B
#define N_PANELS ((N_TOT + 127) / 128)             // 395 row panels

// ---------------------------------------------------------------------------
// fp32 GEMM: C[N,M] = A[N,K] @ B[K,M]. 128(rows)x64(cols) tile, BK=16,
// 256 threads, 8x4 microtile. XCD-aware 1D grid: the 4 col-tiles of each
// row-panel get ids == c (mod 8) -> same XCD -> A-panel served from that
// XCD's L2 after the first tile fetches it (R8 showed 96 MB refetch when
// col-tiles round-robin across XCDs).
// ---------------------------------------------------------------------------
template <bool LRELU>
__global__ __launch_bounds__(256) void gemm_kernel(
    const float* __restrict__ A, const float* __restrict__ B,
    float* __restrict__ C, int Nn, int K, int M) {
  // ---- XCD swizzle decode: b = c + 8*(q*4 + x), y = q*8 + c ----
  const int b = blockIdx.x;
  const int c = b & 7;
  const int t = b >> 3;
  const int q = t >> 2;
  const int x = t & 3;
  const int y = q * 8 + c;
  if (y >= (Nn + 127) >> 7) return;  // padded tail blocks
  const int colBase = x * 64;
  const int rowBase = y * 128;

  __shared__ float As[16][LDPA];  // [k][row 0..127]
  __shared__ float Bs[16][LDPB];  // [k][col 0..63]
  const int tid = threadIdx.x;
  const int tx = tid & 15;   // col group: cols tx*4..+3
  const int ty = tid >> 4;   // row group: rows ty*8..+7

  // staging coords
  const int sar = tid >> 1;        // A: row 0..127
  const int sak = (tid & 1) * 8;   // A: k offset 0 or 8 (two float4s)
  const int sbk = tid >> 4;        // B: k 0..15
  const int sbc = (tid & 15) * 4;  // B: col 0..60

  float acc[8][4] = {};

  for (int k0 = 0; k0 < K; k0 += 16) {
    // ---- stage A: 128 rows x 16 k; 2 float4s per thread ----
    {
      int gr = rowBase + sar;
      const float* Ar = A + (long)gr * K;
#pragma unroll
      for (int h = 0; h < 2; ++h) {
        int gk = k0 + sak + h * 4;
        float4 v = {0.f, 0.f, 0.f, 0.f};
        if (gr < Nn) {
          if (gk + 3 < K) {
            v = *reinterpret_cast<const float4*>(Ar + gk);
          } else {
            v.x = (gk + 0 < K) ? Ar[gk + 0] : 0.f;
            v.y = (gk + 1 < K) ? Ar[gk + 1] : 0.f;
            v.z = (gk + 2 < K) ? Ar[gk + 2] : 0.f;
            v.w = (gk + 3 < K) ? Ar[gk + 3] : 0.f;
          }
        }
        As[sak + h * 4 + 0][sar] = v.x;
        As[sak + h * 4 + 1][sar] = v.y;
        As[sak + h * 4 + 2][sar] = v.z;
        As[sak + h * 4 + 3][sar] = v.w;
      }
    }
    // ---- stage B: 16 k x 64 cols; 1 float4 per thread ----
    {
      float4 v = {0.f, 0.f, 0.f, 0.f};
      int gk = k0 + sbk;
      int gc = colBase + sbc;
      if (gk < K) {
        if (gc + 3 < M) {
          v = *reinterpret_cast<const float4*>(B + (long)gk * M + gc);
        } else {
          v.x = (gc + 0 < M) ? B[(long)gk * M + gc + 0] : 0.f;
          v.y = (gc + 1 < M) ? B[(long)gk * M + gc + 1] : 0.f;
          v.z = (gc + 2 < M) ? B[(long)gk * M + gc + 2] : 0.f;
          v.w = (gc + 3 < M) ? B[(long)gk * M + gc + 3] : 0.f;
        }
      }
      *reinterpret_cast<float4*>(&Bs[sbk][sbc]) = v;
    }
    __syncthreads();

#pragma unroll
    for (int kk = 0; kk < 16; ++kk) {
      float4 a0 = *reinterpret_cast<const float4*>(&As[kk][ty * 8]);
      float4 a1 = *reinterpret_cast<const float4*>(&As[kk][ty * 8 + 4]);
      float4 b4 = *reinterpret_cast<const float4*>(&Bs[kk][tx * 4]);
      acc[0][0] += a0.x * b4.x; acc[0][1] += a0.x * b4.y;
      acc[0][2] += a0.x * b4.z; acc[0][3] += a0.x * b4.w;
      acc[1][0] += a0.y * b4.x; acc[1][1] += a0.y * b4.y;
      acc[1][2] += a0.y * b4.z; acc[1][3] += a0.y * b4.w;
      acc[2][0] += a0.z * b4.x; acc[2][1] += a0.z * b4.y;
      acc[2][2] += a0.z * b4.z; acc[2][3] += a0.z * b4.w;
      acc[3][0] += a0.w * b4.x; acc[3][1] += a0.w * b4.y;
      acc[3][2] += a0.w * b4.z; acc[3][3] += a0.w * b4.w;
      acc[4][0] += a1.x * b4.x; acc[4][1] += a1.x * b4.y;
      acc[4][2] += a1.x * b4.z; acc[4][3] += a1.x * b4.w;
      acc[5][0] += a1.y * b4.x; acc[5][1] += a1.y * b4.y;
      acc[5][2] += a1.y * b4.z; acc[5][3] += a1.y * b4.w;
      acc[6][0] += a1.z * b4.x; acc[6][1] += a1.z * b4.y;
      acc[6][2] += a1.z * b4.z; acc[6][3] += a1.z * b4.w;
      acc[7][0] += a1.w * b4.x; acc[7][1] += a1.w * b4.y;
      acc[7][2] += a1.w * b4.z; acc[7][3] += a1.w * b4.w;
    }
    __syncthreads();
  }

  // ---- write C: 8 rows x one float4 (M % 4 == 0) ----
  const int gc = colBase + tx * 4;
  if (gc + 3 < M) {
#pragma unroll
    for (int i = 0; i < 8; ++i) {
      int gr = rowBase + ty * 8 + i;
      if (gr < Nn) {
        float4 o = {acc[i][0], acc[i][1], acc[i][2], acc[i][3]};
        if (LRELU) {
          o.x = o.x > 0.f ? o.x : ALPHA * o.x;
          o.y = o.y > 0.f ? o.y : ALPHA * o.y;
          o.z = o.z > 0.f ? o.z : ALPHA * o.z;
          o.w = o.w > 0.f ? o.w : ALPHA * o.w;
        }
        *reinterpret_cast<float4*>(C + (long)gr * M + gc) = o;
      }
    }
  }
}

// ---------------------------------------------------------------------------
// CSR build: histogram -> 3-kernel exclusive scan -> fill. (unchanged)
// ---------------------------------------------------------------------------
__global__ __launch_bounds__(256) void hist_kernel(const int* __restrict__ dst,
                                                   int* __restrict__ counts) {
  int e = blockIdx.x * blockDim.x + threadIdx.x;
  if (e < E_NUM) atomicAdd(&counts[dst[e]], 1);
}

__global__ __launch_bounds__(SCAN_B) void scan1_kernel(
    const int* __restrict__ counts, int* __restrict__ starts,
    int* __restrict__ blockSums) {
  __shared__ int s[SCAN_B];
  int i = blockIdx.x * SCAN_B + threadIdx.x;
  int v = (i < N_TOT) ? counts[i] : 0;
  s[threadIdx.x] = v;
  __syncthreads();
  for (int off = 1; off < SCAN_B; off <<= 1) {
    int t = (threadIdx.x >= off) ? s[threadIdx.x - off] : 0;
    __syncthreads();
    s[threadIdx.x] += t;
    __syncthreads();
  }
  if (i < N_TOT) starts[i] = s[threadIdx.x] - v;
  if (threadIdx.x == SCAN_B - 1) blockSums[blockIdx.x] = s[threadIdx.x];
}

__global__ __launch_bounds__(SCAN_B) void scan2_kernel(
    int* __restrict__ blockSums) {
  __shared__ int s[SCAN_B];
  int v = (threadIdx.x < NBLK_SCAN) ? blockSums[threadIdx.x] : 0;
  s[threadIdx.x] = v;
  __syncthreads();
  for (int off = 1; off < SCAN_B; off <<= 1) {
    int t = (threadIdx.x >= off) ? s[threadIdx.x - off] : 0;
    __syncthreads();
    s[threadIdx.x] += t;
    __syncthreads();
  }
  if (threadIdx.x < NBLK_SCAN) blockSums[threadIdx.x] = s[threadIdx.x] - v;
}

__global__ __launch_bounds__(SCAN_B) void scan3_kernel(
    int* __restrict__ starts, const int* __restrict__ blockSums,
    int* __restrict__ cursor) {
  int i = blockIdx.x * SCAN_B + threadIdx.x;
  if (i < N_TOT) {
    int st = starts[i] + blockSums[blockIdx.x];
    starts[i] = st;
    cursor[i] = st;
  }
}

__global__ __launch_bounds__(256) void fill_kernel(
    const int* __restrict__ src, const int* __restrict__ dst,
    const float* __restrict__ vals, int* __restrict__ cursor,
    int* __restrict__ csrSrc, float* __restrict__ csrVal) {
  int e = blockIdx.x * blockDim.x + threadIdx.x;
  if (e >= E_NUM) return;
  int d = dst[e];
  int pos = atomicAdd(&cursor[d], 1);
  csrSrc[pos] = src[e];
  csrVal[pos] = vals[e];
}

// ---------------------------------------------------------------------------
// Pure pull aggregation, one wave per row, 4x unroll. (unchanged)
// ---------------------------------------------------------------------------
template <int CHUNKS>
__global__ __launch_bounds__(256) void agg_kernel(
    const float* __restrict__ h, const int* __restrict__ starts,
    const int* __restrict__ counts, const int* __restrict__ csrSrc,
    const float* __restrict__ csrVal, float* __restrict__ out) {
  const int wave = threadIdx.x >> 6;
  const int lane = threadIdx.x & 63;
  const int row = blockIdx.x * 4 + wave;
  if (row >= N_TOT) return;
  const int st = starts[row];
  const int cnt = counts[row];
  const float4* __restrict__ h4 = reinterpret_cast<const float4*>(h);

  float4 acc = {0.f, 0.f, 0.f, 0.f};
  int j = 0;
  for (; j + 3 < cnt; j += 4) {
    int s0 = csrSrc[st + j + 0], s1 = csrSrc[st + j + 1];
    int s2 = csrSrc[st + j + 2], s3 = csrSrc[st + j + 3];
    float v0 = csrVal[st + j + 0], v1 = csrVal[st + j + 1];
    float v2 = csrVal[st + j + 2], v3 = csrVal[st + j + 3];
    if (lane < CHUNKS) {
      float4 a = h4[(long)s0 * CHUNKS + lane];
      float4 b = h4[(long)s1 * CHUNKS + lane];
      float4 c = h4[(long)s2 * CHUNKS + lane];
      float4 d = h4[(long)s3 * CHUNKS + lane];
      acc.x += a.x * v0 + b.x * v1 + c.x * v2 + d.x * v3;
      acc.y += a.y * v0 + b.y * v1 + c.y * v2 + d.y * v3;
      acc.z += a.z * v0 + b.z * v1 + c.z * v2 + d.z * v3;
      acc.w += a.w * v0 + b.w * v1 + c.w * v2 + d.w * v3;
    }
  }
  for (; j < cnt; ++j) {
    int s0 = csrSrc[st + j];
    float v0 = csrVal[st + j];
    if (lane < CHUNKS) {
      float4 a = h4[(long)s0 * CHUNKS + lane];
      acc.x += a.x * v0;
      acc.y += a.y * v0;
      acc.z += a.z * v0;
      acc.w += a.w * v0;
    }
  }
  if (lane < CHUNKS)
    reinterpret_cast<float4*>(out)[(long)row * CHUNKS + lane] = acc;
}

// ---------------------------------------------------------------------------
// Fused LeakyReLU + L2 row-normalize, in place. (unchanged)
// ---------------------------------------------------------------------------
__global__ __launch_bounds__(256) void norm_kernel(float* __restrict__ x) {
  const int wave = threadIdx.x >> 6;
  const int lane = threadIdx.x & 63;
  const int row = blockIdx.x * 4 + wave;
  if (row >= N_TOT) return;
  float* p = x + (long)row * D_HID;
  float4 v = {0.f, 0.f, 0.f, 0.f};
  if (lane < 50) {
    v = *reinterpret_cast<float4*>(p + lane * 4);
    v.x = v.x > 0.f ? v.x : ALPHA * v.x;
    v.y = v.y > 0.f ? v.y : ALPHA * v.y;
    v.z = v.z > 0.f ? v.z : ALPHA * v.z;
    v.w = v.w > 0.f ? v.w : ALPHA * v.w;
  }
  float ss = v.x * v.x + v.y * v.y + v.z * v.z + v.w * v.w;
#pragma unroll
  for (int off = 32; off; off >>= 1) ss += __shfl_xor(ss, off);
  float inv = 1.f / fmaxf(sqrtf(ss), EPS_);
  if (lane < 50) {
    float4 o = {v.x * inv, v.y * inv, v.z * inv, v.w * inv};
    *reinterpret_cast<float4*>(p + lane * 4) = o;
  }
}

// ---------------------------------------------------------------------------
extern "C" void kernel_launch(void* const* d_in, const int* in_sizes, int n_in,
                              void* d_out, int out_size, void* d_ws,
                              size_t ws_size, hipStream_t stream) {
  const float* emb = (const float*)d_in[0];   // [N_TOT, 100]
  const float* W1 = (const float*)d_in[1];    // [100, 200]
  const float* W2 = (const float*)d_in[2];    // [200, 200]
  const int* eidx = (const int*)d_in[3];      // [2, E]
  const float* vals = (const float*)d_in[4];  // [E]
  const int* src = eidx;
  const int* dst = eidx + E_NUM;
  float* out = (float*)d_out;                 // [N_TOT, 200] flat

  // ---- workspace layout (~68 MB) ----
  char* p = (char*)d_ws;
  auto take = [&](size_t bytes) {
    char* r = p;
    p += (bytes + 255) & ~(size_t)255;
    return r;
  };
  float* g1 = (float*)take((size_t)N_TOT * D_IN_ * sizeof(float));   // 20.2 MB
  float* g2 = (float*)take((size_t)N_TOT * D_HID * sizeof(float));   // 40.4 MB
  int* csrSrc = (int*)take((size_t)E_NUM * sizeof(int));
  float* csrVal = (float*)take((size_t)E_NUM * sizeof(float));
  int* counts = (int*)take((size_t)N_TOT * sizeof(int));
  int* starts = (int*)take((size_t)N_TOT * sizeof(int));
  int* cursor = (int*)take((size_t)N_TOT * sizeof(int));
  int* blockSums = (int*)take((size_t)NBLK_SCAN * sizeof(int));

  const int eBlocks = (E_NUM + 255) / 256;
  const int rowWaveBlocks = (N_TOT + 3) / 4;

  // ---- CSR build (once; shared by both layers) ----
  hipMemsetAsync(counts, 0, (size_t)N_TOT * sizeof(int), stream);
  hist_kernel<<<eBlocks, 256, 0, stream>>>(dst, counts);
  scan1_kernel<<<NBLK_SCAN, SCAN_B, 0, stream>>>(counts, starts, blockSums);
  scan2_kernel<<<1, SCAN_B, 0, stream>>>(blockSums);
  scan3_kernel<<<NBLK_SCAN, SCAN_B, 0, stream>>>(starts, blockSums, cursor);
  fill_kernel<<<eBlocks, 256, 0, stream>>>(src, dst, vals, cursor, csrSrc,
                                           csrVal);

  // XCD-swizzled 1D gemm grid: 8 xcd slots x ceil(395/8) panels x 4 col tiles
  const int gemmBlocks = 8 * ((N_PANELS + 7) / 8) * 4;  // 1600 (20 no-ops)

  // ---- layer 1: aggregate emb in 100-dim, then project (+lrelu) ----
  agg_kernel<25><<<rowWaveBlocks, 256, 0, stream>>>(emb, starts, counts,
                                                    csrSrc, csrVal, g1);
  gemm_kernel<true><<<gemmBlocks, 256, 0, stream>>>(g1, W1, out /*h1*/, N_TOT,
                                                    D_IN_, D_HID);

  // ---- layer 2: aggregate h1, project, then lrelu+normalize ----
  agg_kernel<50><<<rowWaveBlocks, 256, 0, stream>>>(out, starts, counts,
                                                    csrSrc, csrVal, g2);
  gemm_kernel<false><<<gemmBlocks, 256, 0, stream>>>(g2, W2, out, N_TOT,
                                                     D_HID, D_HID);
  norm_kernel<<<rowWaveBlocks, 256, 0, stream>>>(out);
}

// Round 14
// 442.256 us; speedup vs baseline: 1.1060x; 1.0897x over previous
//
#include <hip/hip_runtime.h>

#define N_TOT 50500
#define E_NUM 800000
#define D_IN_ 100
#define D_HID 200
#define ALPHA 0.2f
#define EPS_ 1e-12f
#define SCAN_B 256
#define NBLK_SCAN ((N_TOT + SCAN_B - 1) / SCAN_B)  // 198
#define LDPA 132  // A row-dim pad: 132*4 = 528 B
#define LDPB 68   // B col-dim pad: 68*4 = 272 B
#define N_PANELS ((N_TOT + 127) / 128)             // 395 row panels

// ---- fp32 <-> bf16 helpers (RNE pack; shift-only unpack) ----
__device__ __forceinline__ unsigned short f2bf(float f) {
  unsigned u = __float_as_uint(f);
  u += 0x7FFFu + ((u >> 16) & 1u);
  return (unsigned short)(u >> 16);
}
__device__ __forceinline__ float bf2f(unsigned short s) {
  return __uint_as_float(((unsigned)s) << 16);
}

// ---------------------------------------------------------------------------
// fp32 GEMM: C[N,M] = A[N,K] @ B[K,M]. 128x64 tile, BK=16, 8x4 microtile,
// XCD-swizzled 1D grid. OUTBF16 epilogue packs bf16.
// ---------------------------------------------------------------------------
template <bool LRELU, bool OUTBF16>
__global__ __launch_bounds__(256) void gemm_kernel(
    const float* __restrict__ A, const float* __restrict__ B, void* Cv,
    int Nn, int K, int M) {
  const int b = blockIdx.x;
  const int c = b & 7;
  const int t = b >> 3;
  const int q = t >> 2;
  const int x = t & 3;
  const int y = q * 8 + c;
  if (y >= (Nn + 127) >> 7) return;
  const int colBase = x * 64;
  const int rowBase = y * 128;

  __shared__ float As[16][LDPA];
  __shared__ float Bs[16][LDPB];
  const int tid = threadIdx.x;
  const int tx = tid & 15;
  const int ty = tid >> 4;

  const int sar = tid >> 1;
  const int sak = (tid & 1) * 8;
  const int sbk = tid >> 4;
  const int sbc = (tid & 15) * 4;

  float acc[8][4] = {};

  for (int k0 = 0; k0 < K; k0 += 16) {
    {
      int gr = rowBase + sar;
      const float* Ar = A + (long)gr * K;
#pragma unroll
      for (int h = 0; h < 2; ++h) {
        int gk = k0 + sak + h * 4;
        float4 v = {0.f, 0.f, 0.f, 0.f};
        if (gr < Nn) {
          if (gk + 3 < K) {
            v = *reinterpret_cast<const float4*>(Ar + gk);
          } else {
            v.x = (gk + 0 < K) ? Ar[gk + 0] : 0.f;
            v.y = (gk + 1 < K) ? Ar[gk + 1] : 0.f;
            v.z = (gk + 2 < K) ? Ar[gk + 2] : 0.f;
            v.w = (gk + 3 < K) ? Ar[gk + 3] : 0.f;
          }
        }
        As[sak + h * 4 + 0][sar] = v.x;
        As[sak + h * 4 + 1][sar] = v.y;
        As[sak + h * 4 + 2][sar] = v.z;
        As[sak + h * 4 + 3][sar] = v.w;
      }
    }
    {
      float4 v = {0.f, 0.f, 0.f, 0.f};
      int gk = k0 + sbk;
      int gc = colBase + sbc;
      if (gk < K) {
        if (gc + 3 < M) {
          v = *reinterpret_cast<const float4*>(B + (long)gk * M + gc);
        } else {
          v.x = (gc + 0 < M) ? B[(long)gk * M + gc + 0] : 0.f;
          v.y = (gc + 1 < M) ? B[(long)gk * M + gc + 1] : 0.f;
          v.z = (gc + 2 < M) ? B[(long)gk * M + gc + 2] : 0.f;
          v.w = (gc + 3 < M) ? B[(long)gk * M + gc + 3] : 0.f;
        }
      }
      *reinterpret_cast<float4*>(&Bs[sbk][sbc]) = v;
    }
    __syncthreads();

#pragma unroll
    for (int kk = 0; kk < 16; ++kk) {
      float4 a0 = *reinterpret_cast<const float4*>(&As[kk][ty * 8]);
      float4 a1 = *reinterpret_cast<const float4*>(&As[kk][ty * 8 + 4]);
      float4 b4 = *reinterpret_cast<const float4*>(&Bs[kk][tx * 4]);
      acc[0][0] += a0.x * b4.x; acc[0][1] += a0.x * b4.y;
      acc[0][2] += a0.x * b4.z; acc[0][3] += a0.x * b4.w;
      acc[1][0] += a0.y * b4.x; acc[1][1] += a0.y * b4.y;
      acc[1][2] += a0.y * b4.z; acc[1][3] += a0.y * b4.w;
      acc[2][0] += a0.z * b4.x; acc[2][1] += a0.z * b4.y;
      acc[2][2] += a0.z * b4.z; acc[2][3] += a0.z * b4.w;
      acc[3][0] += a0.w * b4.x; acc[3][1] += a0.w * b4.y;
      acc[3][2] += a0.w * b4.z; acc[3][3] += a0.w * b4.w;
      acc[4][0] += a1.x * b4.x; acc[4][1] += a1.x * b4.y;
      acc[4][2] += a1.x * b4.z; acc[4][3] += a1.x * b4.w;
      acc[5][0] += a1.y * b4.x; acc[5][1] += a1.y * b4.y;
      acc[5][2] += a1.y * b4.z; acc[5][3] += a1.y * b4.w;
      acc[6][0] += a1.z * b4.x; acc[6][1] += a1.z * b4.y;
      acc[6][2] += a1.z * b4.z; acc[6][3] += a1.z * b4.w;
      acc[7][0] += a1.w * b4.x; acc[7][1] += a1.w * b4.y;
      acc[7][2] += a1.w * b4.z; acc[7][3] += a1.w * b4.w;
    }
    __syncthreads();
  }

  const int gc = colBase + tx * 4;
  if (gc + 3 < M) {
#pragma unroll
    for (int i = 0; i < 8; ++i) {
      int gr = rowBase + ty * 8 + i;
      if (gr < Nn) {
        float4 o = {acc[i][0], acc[i][1], acc[i][2], acc[i][3]};
        if (LRELU) {
          o.x = o.x > 0.f ? o.x : ALPHA * o.x;
          o.y = o.y > 0.f ? o.y : ALPHA * o.y;
          o.z = o.z > 0.f ? o.z : ALPHA * o.z;
          o.w = o.w > 0.f ? o.w : ALPHA * o.w;
        }
        if (OUTBF16) {
          ushort4 ob = {f2bf(o.x), f2bf(o.y), f2bf(o.z), f2bf(o.w)};
          *reinterpret_cast<ushort4*>((unsigned short*)Cv + (long)gr * M +
                                      gc) = ob;
        } else {
          *reinterpret_cast<float4*>((float*)Cv + (long)gr * M + gc) = o;
        }
      }
    }
  }
}

// ---------------------------------------------------------------------------
// CSR build: histogram -> 3-kernel exclusive scan -> fill. (unchanged)
// ---------------------------------------------------------------------------
__global__ __launch_bounds__(256) void hist_kernel(const int* __restrict__ dst,
                                                   int* __restrict__ counts) {
  int e = blockIdx.x * blockDim.x + threadIdx.x;
  if (e < E_NUM) atomicAdd(&counts[dst[e]], 1);
}

__global__ __launch_bounds__(SCAN_B) void scan1_kernel(
    const int* __restrict__ counts, int* __restrict__ starts,
    int* __restrict__ blockSums) {
  __shared__ int s[SCAN_B];
  int i = blockIdx.x * SCAN_B + threadIdx.x;
  int v = (i < N_TOT) ? counts[i] : 0;
  s[threadIdx.x] = v;
  __syncthreads();
  for (int off = 1; off < SCAN_B; off <<= 1) {
    int t = (threadIdx.x >= off) ? s[threadIdx.x - off] : 0;
    __syncthreads();
    s[threadIdx.x] += t;
    __syncthreads();
  }
  if (i < N_TOT) starts[i] = s[threadIdx.x] - v;
  if (threadIdx.x == SCAN_B - 1) blockSums[blockIdx.x] = s[threadIdx.x];
}

__global__ __launch_bounds__(SCAN_B) void scan2_kernel(
    int* __restrict__ blockSums) {
  __shared__ int s[SCAN_B];
  int v = (threadIdx.x < NBLK_SCAN) ? blockSums[threadIdx.x] : 0;
  s[threadIdx.x] = v;
  __syncthreads();
  for (int off = 1; off < SCAN_B; off <<= 1) {
    int t = (threadIdx.x >= off) ? s[threadIdx.x - off] : 0;
    __syncthreads();
    s[threadIdx.x] += t;
    __syncthreads();
  }
  if (threadIdx.x < NBLK_SCAN) blockSums[threadIdx.x] = s[threadIdx.x] - v;
}

__global__ __launch_bounds__(SCAN_B) void scan3_kernel(
    int* __restrict__ starts, const int* __restrict__ blockSums,
    int* __restrict__ cursor) {
  int i = blockIdx.x * SCAN_B + threadIdx.x;
  if (i < N_TOT) {
    int st = starts[i] + blockSums[blockIdx.x];
    starts[i] = st;
    cursor[i] = st;
  }
}

__global__ __launch_bounds__(256) void fill_kernel(
    const int* __restrict__ src, const int* __restrict__ dst,
    const float* __restrict__ vals, int* __restrict__ cursor,
    int* __restrict__ csrSrc, float* __restrict__ csrVal) {
  int e = blockIdx.x * blockDim.x + threadIdx.x;
  if (e >= E_NUM) return;
  int d = dst[e];
  int pos = atomicAdd(&cursor[d], 1);
  csrSrc[pos] = src[e];
  csrVal[pos] = vals[e];
}

// ---------------------------------------------------------------------------
// Layer-1 pull aggregation from fp32 (CHUNKS=25).
// ---------------------------------------------------------------------------
template <int CHUNKS>
__global__ __launch_bounds__(256) void agg_kernel(
    const float* __restrict__ h, const int* __restrict__ starts,
    const int* __restrict__ counts, const int* __restrict__ csrSrc,
    const float* __restrict__ csrVal, float* __restrict__ out) {
  const int wave = threadIdx.x >> 6;
  const int lane = threadIdx.x & 63;
  const int row = blockIdx.x * 4 + wave;
  if (row >= N_TOT) return;
  const int st = starts[row];
  const int cnt = counts[row];
  const float4* __restrict__ h4 = reinterpret_cast<const float4*>(h);

  float4 acc = {0.f, 0.f, 0.f, 0.f};
  int j = 0;
  for (; j + 3 < cnt; j += 4) {
    int s0 = csrSrc[st + j + 0], s1 = csrSrc[st + j + 1];
    int s2 = csrSrc[st + j + 2], s3 = csrSrc[st + j + 3];
    float v0 = csrVal[st + j + 0], v1 = csrVal[st + j + 1];
    float v2 = csrVal[st + j + 2], v3 = csrVal[st + j + 3];
    if (lane < CHUNKS) {
      float4 a = h4[(long)s0 * CHUNKS + lane];
      float4 b = h4[(long)s1 * CHUNKS + lane];
      float4 c = h4[(long)s2 * CHUNKS + lane];
      float4 d = h4[(long)s3 * CHUNKS + lane];
      acc.x += a.x * v0 + b.x * v1 + c.x * v2 + d.x * v3;
      acc.y += a.y * v0 + b.y * v1 + c.y * v2 + d.y * v3;
      acc.z += a.z * v0 + b.z * v1 + c.z * v2 + d.z * v3;
      acc.w += a.w * v0 + b.w * v1 + c.w * v2 + d.w * v3;
    }
  }
  for (; j < cnt; ++j) {
    int s0 = csrSrc[st + j];
    float v0 = csrVal[st + j];
    if (lane < CHUNKS) {
      float4 a = h4[(long)s0 * CHUNKS + lane];
      acc.x += a.x * v0;
      acc.y += a.y * v0;
      acc.z += a.z * v0;
      acc.w += a.w * v0;
    }
  }
  if (lane < CHUNKS)
    reinterpret_cast<float4*>(out)[(long)row * CHUNKS + lane] = acc;
}

// ---------------------------------------------------------------------------
// Layer-2 pull aggregation from bf16 h1 (ushort4 = 4 elems / 8 B per lane;
// 50 lanes cover the 200-wide row = 400 B per edge burst). Halves the
// gather traffic that dominated R11's profile (agg<50>: 322 MB FETCH).
// ---------------------------------------------------------------------------
__global__ __launch_bounds__(256) void agg2_bf16_kernel(
    const unsigned short* __restrict__ h, const int* __restrict__ starts,
    const int* __restrict__ counts, const int* __restrict__ csrSrc,
    const float* __restrict__ csrVal, float* __restrict__ out) {
  const int wave = threadIdx.x >> 6;
  const int lane = threadIdx.x & 63;
  const int row = blockIdx.x * 4 + wave;
  if (row >= N_TOT) return;
  const int st = starts[row];
  const int cnt = counts[row];
  const ushort4* __restrict__ h4 = reinterpret_cast<const ushort4*>(h);

  float4 acc = {0.f, 0.f, 0.f, 0.f};
  int j = 0;
  for (; j + 3 < cnt; j += 4) {
    int s0 = csrSrc[st + j + 0], s1 = csrSrc[st + j + 1];
    int s2 = csrSrc[st + j + 2], s3 = csrSrc[st + j + 3];
    float v0 = csrVal[st + j + 0], v1 = csrVal[st + j + 1];
    float v2 = csrVal[st + j + 2], v3 = csrVal[st + j + 3];
    if (lane < 50) {
      ushort4 a = h4[(long)s0 * 50 + lane];
      ushort4 b = h4[(long)s1 * 50 + lane];
      ushort4 c = h4[(long)s2 * 50 + lane];
      ushort4 d = h4[(long)s3 * 50 + lane];
      acc.x += bf2f(a.x) * v0 + bf2f(b.x) * v1 + bf2f(c.x) * v2 +
               bf2f(d.x) * v3;
      acc.y += bf2f(a.y) * v0 + bf2f(b.y) * v1 + bf2f(c.y) * v2 +
               bf2f(d.y) * v3;
      acc.z += bf2f(a.z) * v0 + bf2f(b.z) * v1 + bf2f(c.z) * v2 +
               bf2f(d.z) * v3;
      acc.w += bf2f(a.w) * v0 + bf2f(b.w) * v1 + bf2f(c.w) * v2 +
               bf2f(d.w) * v3;
    }
  }
  for (; j < cnt; ++j) {
    int s0 = csrSrc[st + j];
    float v0 = csrVal[st + j];
    if (lane < 50) {
      ushort4 a = h4[(long)s0 * 50 + lane];
      acc.x += bf2f(a.x) * v0;
      acc.y += bf2f(a.y) * v0;
      acc.z += bf2f(a.z) * v0;
      acc.w += bf2f(a.w) * v0;
    }
  }
  if (lane < 50)
    reinterpret_cast<float4*>(out)[(long)row * 50 + lane] = acc;
}

// ---------------------------------------------------------------------------
// Fused LeakyReLU + L2 row-normalize, in place. (unchanged)
// ---------------------------------------------------------------------------
__global__ __launch_bounds__(256) void norm_kernel(float* __restrict__ x) {
  const int wave = threadIdx.x >> 6;
  const int lane = threadIdx.x & 63;
  const int row = blockIdx.x * 4 + wave;
  if (row >= N_TOT) return;
  float* p = x + (long)row * D_HID;
  float4 v = {0.f, 0.f, 0.f, 0.f};
  if (lane < 50) {
    v = *reinterpret_cast<float4*>(p + lane * 4);
    v.x = v.x > 0.f ? v.x : ALPHA * v.x;
    v.y = v.y > 0.f ? v.y : ALPHA * v.y;
    v.z = v.z > 0.f ? v.z : ALPHA * v.z;
    v.w = v.w > 0.f ? v.w : ALPHA * v.w;
  }
  float ss = v.x * v.x + v.y * v.y + v.z * v.z + v.w * v.w;
#pragma unroll
  for (int off = 32; off; off >>= 1) ss += __shfl_xor(ss, off);
  float inv = 1.f / fmaxf(sqrtf(ss), EPS_);
  if (lane < 50) {
    float4 o = {v.x * inv, v.y * inv, v.z * inv, v.w * inv};
    *reinterpret_cast<float4*>(p + lane * 4) = o;
  }
}

// ---------------------------------------------------------------------------
extern "C" void kernel_launch(void* const* d_in, const int* in_sizes, int n_in,
                              void* d_out, int out_size, void* d_ws,
                              size_t ws_size, hipStream_t stream) {
  const float* emb = (const float*)d_in[0];   // [N_TOT, 100]
  const float* W1 = (const float*)d_in[1];    // [100, 200]
  const float* W2 = (const float*)d_in[2];    // [200, 200]
  const int* eidx = (const int*)d_in[3];      // [2, E]
  const float* vals = (const float*)d_in[4];  // [E]
  const int* src = eidx;
  const int* dst = eidx + E_NUM;
  float* out = (float*)d_out;                 // [N_TOT, 200] flat

  // h1 (bf16, 20.2 MB) lives in the FRONT HALF of d_out: written by gemm1,
  // consumed by agg2, dead before gemm2 overwrites d_out. No aliasing.
  unsigned short* h1b = (unsigned short*)d_out;

  // ---- workspace layout (~68 MB, same as R12) ----
  char* p = (char*)d_ws;
  auto take = [&](size_t bytes) {
    char* r = p;
    p += (bytes + 255) & ~(size_t)255;
    return r;
  };
  float* g1 = (float*)take((size_t)N_TOT * D_IN_ * sizeof(float));   // 20.2 MB
  float* g2 = (float*)take((size_t)N_TOT * D_HID * sizeof(float));   // 40.4 MB
  int* csrSrc = (int*)take((size_t)E_NUM * sizeof(int));
  float* csrVal = (float*)take((size_t)E_NUM * sizeof(float));
  int* counts = (int*)take((size_t)N_TOT * sizeof(int));
  int* starts = (int*)take((size_t)N_TOT * sizeof(int));
  int* cursor = (int*)take((size_t)N_TOT * sizeof(int));
  int* blockSums = (int*)take((size_t)NBLK_SCAN * sizeof(int));

  const int eBlocks = (E_NUM + 255) / 256;
  const int rowWaveBlocks = (N_TOT + 3) / 4;

  // ---- CSR build (once; shared by both layers) ----
  hipMemsetAsync(counts, 0, (size_t)N_TOT * sizeof(int), stream);
  hist_kernel<<<eBlocks, 256, 0, stream>>>(dst, counts);
  scan1_kernel<<<NBLK_SCAN, SCAN_B, 0, stream>>>(counts, starts, blockSums);
  scan2_kernel<<<1, SCAN_B, 0, stream>>>(blockSums);
  scan3_kernel<<<NBLK_SCAN, SCAN_B, 0, stream>>>(starts, blockSums, cursor);
  fill_kernel<<<eBlocks, 256, 0, stream>>>(src, dst, vals, cursor, csrSrc,
                                           csrVal);

  const int gemmBlocks = 8 * ((N_PANELS + 7) / 8) * 4;  // 1600

  // ---- layer 1: agg in 100-dim -> project (+lrelu) -> bf16 h1 ----
  agg_kernel<25><<<rowWaveBlocks, 256, 0, stream>>>(emb, starts, counts,
                                                    csrSrc, csrVal, g1);
  gemm_kernel<true, true><<<gemmBlocks, 256, 0, stream>>>(
      g1, W1, (void*)h1b, N_TOT, D_IN_, D_HID);

  // ---- layer 2: bf16 gather-agg -> project -> lrelu+normalize ----
  agg2_bf16_kernel<<<rowWaveBlocks, 256, 0, stream>>>(h1b, starts, counts,
                                                      csrSrc, csrVal, g2);
  gemm_kernel<false, false><<<gemmBlocks, 256, 0, stream>>>(
      g2, W2, (void*)out, N_TOT, D_HID, D_HID);
  norm_kernel<<<rowWaveBlocks, 256, 0, stream>>>(out);
}

// Round 15
// 374.435 us; speedup vs baseline: 1.3063x; 1.1811x over previous
//
#include <hip/hip_runtime.h>

#define N_TOT 50500
#define E_NUM 800000
#define D_IN_ 100
#define D_HID 200
#define ALPHA 0.2f
#define EPS_ 1e-12f
#define SCAN_B 256
#define NBLK_SCAN ((N_TOT + SCAN_B - 1) / SCAN_B)  // 198
#define LDPA 132  // fp32 gemm A pad
#define LDPB 68   // fp32 gemm B pad
#define N_PANELS ((N_TOT + 127) / 128)

// MFMA gemm2 geometry
#define KP 224   // K=200 padded to 7x32
#define CF 13    // col fragments: 13*16 = 208 >= 200
#define BROW 64  // rows per block (4 waves x 16)
#define LDK 40   // LDS k-stride in bf16 (32 + 8 pad -> 2-way banks, free)

typedef __attribute__((ext_vector_type(8))) short short8x;  // 8 bf16
typedef __attribute__((ext_vector_type(4))) float f32x4;

// ---- fp32 <-> bf16 helpers (RNE pack; shift-only unpack) ----
__device__ __forceinline__ unsigned short f2bf(float f) {
  unsigned u = __float_as_uint(f);
  u += 0x7FFFu + ((u >> 16) & 1u);
  return (unsigned short)(u >> 16);
}
__device__ __forceinline__ float bf2f(unsigned short s) {
  return __uint_as_float(((unsigned)s) << 16);
}

// ---------------------------------------------------------------------------
// fp32 GEMM (layer 1 only): 128x64 tile, BK=16, 8x4 microtile, XCD-swizzled
// 1D grid, bf16-packing epilogue. (unchanged from R13)
// ---------------------------------------------------------------------------
template <bool LRELU, bool OUTBF16>
__global__ __launch_bounds__(256) void gemm_kernel(
    const float* __restrict__ A, const float* __restrict__ B, void* Cv,
    int Nn, int K, int M) {
  const int b = blockIdx.x;
  const int c = b & 7;
  const int t = b >> 3;
  const int q = t >> 2;
  const int x = t & 3;
  const int y = q * 8 + c;
  if (y >= (Nn + 127) >> 7) return;
  const int colBase = x * 64;
  const int rowBase = y * 128;

  __shared__ float As[16][LDPA];
  __shared__ float Bs[16][LDPB];
  const int tid = threadIdx.x;
  const int tx = tid & 15;
  const int ty = tid >> 4;

  const int sar = tid >> 1;
  const int sak = (tid & 1) * 8;
  const int sbk = tid >> 4;
  const int sbc = (tid & 15) * 4;

  float acc[8][4] = {};

  for (int k0 = 0; k0 < K; k0 += 16) {
    {
      int gr = rowBase + sar;
      const float* Ar = A + (long)gr * K;
#pragma unroll
      for (int h = 0; h < 2; ++h) {
        int gk = k0 + sak + h * 4;
        float4 v = {0.f, 0.f, 0.f, 0.f};
        if (gr < Nn) {
          if (gk + 3 < K) {
            v = *reinterpret_cast<const float4*>(Ar + gk);
          } else {
            v.x = (gk + 0 < K) ? Ar[gk + 0] : 0.f;
            v.y = (gk + 1 < K) ? Ar[gk + 1] : 0.f;
            v.z = (gk + 2 < K) ? Ar[gk + 2] : 0.f;
            v.w = (gk + 3 < K) ? Ar[gk + 3] : 0.f;
          }
        }
        As[sak + h * 4 + 0][sar] = v.x;
        As[sak + h * 4 + 1][sar] = v.y;
        As[sak + h * 4 + 2][sar] = v.z;
        As[sak + h * 4 + 3][sar] = v.w;
      }
    }
    {
      float4 v = {0.f, 0.f, 0.f, 0.f};
      int gk = k0 + sbk;
      int gc = colBase + sbc;
      if (gk < K) {
        if (gc + 3 < M) {
          v = *reinterpret_cast<const float4*>(B + (long)gk * M + gc);
        } else {
          v.x = (gc + 0 < M) ? B[(long)gk * M + gc + 0] : 0.f;
          v.y = (gc + 1 < M) ? B[(long)gk * M + gc + 1] : 0.f;
          v.z = (gc + 2 < M) ? B[(long)gk * M + gc + 2] : 0.f;
          v.w = (gc + 3 < M) ? B[(long)gk * M + gc + 3] : 0.f;
        }
      }
      *reinterpret_cast<float4*>(&Bs[sbk][sbc]) = v;
    }
    __syncthreads();

#pragma unroll
    for (int kk = 0; kk < 16; ++kk) {
      float4 a0 = *reinterpret_cast<const float4*>(&As[kk][ty * 8]);
      float4 a1 = *reinterpret_cast<const float4*>(&As[kk][ty * 8 + 4]);
      float4 b4 = *reinterpret_cast<const float4*>(&Bs[kk][tx * 4]);
      acc[0][0] += a0.x * b4.x; acc[0][1] += a0.x * b4.y;
      acc[0][2] += a0.x * b4.z; acc[0][3] += a0.x * b4.w;
      acc[1][0] += a0.y * b4.x; acc[1][1] += a0.y * b4.y;
      acc[1][2] += a0.y * b4.z; acc[1][3] += a0.y * b4.w;
      acc[2][0] += a0.z * b4.x; acc[2][1] += a0.z * b4.y;
      acc[2][2] += a0.z * b4.z; acc[2][3] += a0.z * b4.w;
      acc[3][0] += a0.w * b4.x; acc[3][1] += a0.w * b4.y;
      acc[3][2] += a0.w * b4.z; acc[3][3] += a0.w * b4.w;
      acc[4][0] += a1.x * b4.x; acc[4][1] += a1.x * b4.y;
      acc[4][2] += a1.x * b4.z; acc[4][3] += a1.x * b4.w;
      acc[5][0] += a1.y * b4.x; acc[5][1] += a1.y * b4.y;
      acc[5][2] += a1.y * b4.z; acc[5][3] += a1.y * b4.w;
      acc[6][0] += a1.z * b4.x; acc[6][1] += a1.z * b4.y;
      acc[6][2] += a1.z * b4.z; acc[6][3] += a1.z * b4.w;
      acc[7][0] += a1.w * b4.x; acc[7][1] += a1.w * b4.y;
      acc[7][2] += a1.w * b4.z; acc[7][3] += a1.w * b4.w;
    }
    __syncthreads();
  }

  const int gc = colBase + tx * 4;
  if (gc + 3 < M) {
#pragma unroll
    for (int i = 0; i < 8; ++i) {
      int gr = rowBase + ty * 8 + i;
      if (gr < Nn) {
        float4 o = {acc[i][0], acc[i][1], acc[i][2], acc[i][3]};
        if (LRELU) {
          o.x = o.x > 0.f ? o.x : ALPHA * o.x;
          o.y = o.y > 0.f ? o.y : ALPHA * o.y;
          o.z = o.z > 0.f ? o.z : ALPHA * o.z;
          o.w = o.w > 0.f ? o.w : ALPHA * o.w;
        }
        if (OUTBF16) {
          ushort4 ob = {f2bf(o.x), f2bf(o.y), f2bf(o.z), f2bf(o.w)};
          *reinterpret_cast<ushort4*>((unsigned short*)Cv + (long)gr * M +
                                      gc) = ob;
        } else {
          *reinterpret_cast<float4*>((float*)Cv + (long)gr * M + gc) = o;
        }
      }
    }
  }
}

// ---------------------------------------------------------------------------
// W2 -> W2^T in bf16, [CF*16=208 cols][KP=224 k], zero-padded.
// ---------------------------------------------------------------------------
__global__ __launch_bounds__(256) void w2t_kernel(
    const float* __restrict__ W2, unsigned short* __restrict__ BT) {
  int idx = blockIdx.x * 256 + threadIdx.x;
  if (idx >= CF * 16 * KP) return;
  int c = idx / KP, k = idx % KP;
  float v = (c < D_HID && k < D_HID) ? W2[(long)k * D_HID + c] : 0.f;
  BT[idx] = f2bf(v);
}

// ---------------------------------------------------------------------------
// Layer-2 MFMA GEMM + fused LeakyReLU + L2 row-normalize.
// C[N,200] = lrelu(g2b[N,224] @ W2T^T) row-normalized, straight to d_out.
// Block: 64 rows, 4 waves x 16 rows; per wave 1 row-frag x 13 col-frags of
// mfma_f32_16x16x32_bf16. C/D layout per m89: col=lane&15, row=(lane>>4)*4+i.
// Wave owns full rows -> in-register normalize (norm_kernel deleted).
// ---------------------------------------------------------------------------
__global__ __launch_bounds__(256) void gemm2_mfma_kernel(
    const unsigned short* __restrict__ A,   // g2b [N][KP] bf16
    const unsigned short* __restrict__ BT,  // W2T [208][KP] bf16
    float* __restrict__ C) {                // d_out [N][200] fp32
  __shared__ __align__(16) short A_lds[BROW * LDK];
  __shared__ __align__(16) short B_lds[CF * 16 * LDK];
  const int tid = threadIdx.x;
  const int wave = tid >> 6;
  const int lane = tid & 63;
  const int l15 = lane & 15;
  const int lg = lane >> 4;  // 0..3
  const int rowBase = blockIdx.x * BROW;
  const int wRow = rowBase + wave * 16;

  f32x4 acc[CF] = {};

  for (int k0 = 0; k0 < KP; k0 += 32) {
    // ---- stage A: 64 rows x 32 k (8 bf16 = 16 B per thread) ----
    {
      int r = tid >> 2;
      int koff = (tid & 3) * 8;
      int gr = rowBase + r;
      short8x v = {};
      if (gr < N_TOT)
        v = *reinterpret_cast<const short8x*>(A + (long)gr * KP + k0 + koff);
      *reinterpret_cast<short8x*>(&A_lds[r * LDK + koff]) = v;
    }
    // ---- stage B: 208 cols x 32 k ----
    for (int idx = tid; idx < CF * 16 * 4; idx += 256) {
      int col = idx >> 2;
      int koff = (idx & 3) * 8;
      short8x v =
          *reinterpret_cast<const short8x*>(BT + (long)col * KP + k0 + koff);
      *reinterpret_cast<short8x*>(&B_lds[col * LDK + koff]) = v;
    }
    __syncthreads();

    short8x a = *reinterpret_cast<const short8x*>(
        &A_lds[(wave * 16 + l15) * LDK + lg * 8]);
#pragma unroll
    for (int cf = 0; cf < CF; ++cf) {
      short8x b = *reinterpret_cast<const short8x*>(
          &B_lds[(cf * 16 + l15) * LDK + lg * 8]);
      acc[cf] = __builtin_amdgcn_mfma_f32_16x16x32_bf16(a, b, acc[cf], 0, 0, 0);
    }
    __syncthreads();
  }

  if (wRow >= N_TOT) return;  // whole-wave uniform; all barriers done

  // ---- fused epilogue: lrelu -> per-row sum-of-squares -> normalize ----
  float ss[4] = {0.f, 0.f, 0.f, 0.f};
#pragma unroll
  for (int cf = 0; cf < CF; ++cf) {
#pragma unroll
    for (int i = 0; i < 4; ++i) {
      float v = acc[cf][i];
      v = v > 0.f ? v : ALPHA * v;
      acc[cf][i] = v;
      ss[i] += v * v;  // cols >= 200 are exact zeros (padded B) -> no-op
    }
  }
#pragma unroll
  for (int off = 1; off < 16; off <<= 1) {
#pragma unroll
    for (int i = 0; i < 4; ++i) ss[i] += __shfl_xor(ss[i], off);
  }
  float inv[4];
#pragma unroll
  for (int i = 0; i < 4; ++i) inv[i] = 1.f / fmaxf(sqrtf(ss[i]), EPS_);

#pragma unroll
  for (int cf = 0; cf < CF; ++cf) {
    int col = cf * 16 + l15;
    if (col < D_HID) {
#pragma unroll
      for (int i = 0; i < 4; ++i) {
        int gr = wRow + lg * 4 + i;
        if (gr < N_TOT) C[(long)gr * D_HID + col] = acc[cf][i] * inv[i];
      }
    }
  }
}

// ---------------------------------------------------------------------------
// CSR build: histogram -> 3-kernel exclusive scan -> fill. (unchanged)
// ---------------------------------------------------------------------------
__global__ __launch_bounds__(256) void hist_kernel(const int* __restrict__ dst,
                                                   int* __restrict__ counts) {
  int e = blockIdx.x * blockDim.x + threadIdx.x;
  if (e < E_NUM) atomicAdd(&counts[dst[e]], 1);
}

__global__ __launch_bounds__(SCAN_B) void scan1_kernel(
    const int* __restrict__ counts, int* __restrict__ starts,
    int* __restrict__ blockSums) {
  __shared__ int s[SCAN_B];
  int i = blockIdx.x * SCAN_B + threadIdx.x;
  int v = (i < N_TOT) ? counts[i] : 0;
  s[threadIdx.x] = v;
  __syncthreads();
  for (int off = 1; off < SCAN_B; off <<= 1) {
    int t = (threadIdx.x >= off) ? s[threadIdx.x - off] : 0;
    __syncthreads();
    s[threadIdx.x] += t;
    __syncthreads();
  }
  if (i < N_TOT) starts[i] = s[threadIdx.x] - v;
  if (threadIdx.x == SCAN_B - 1) blockSums[blockIdx.x] = s[threadIdx.x];
}

__global__ __launch_bounds__(SCAN_B) void scan2_kernel(
    int* __restrict__ blockSums) {
  __shared__ int s[SCAN_B];
  int v = (threadIdx.x < NBLK_SCAN) ? blockSums[threadIdx.x] : 0;
  s[threadIdx.x] = v;
  __syncthreads();
  for (int off = 1; off < SCAN_B; off <<= 1) {
    int t = (threadIdx.x >= off) ? s[threadIdx.x - off] : 0;
    __syncthreads();
    s[threadIdx.x] += t;
    __syncthreads();
  }
  if (threadIdx.x < NBLK_SCAN) blockSums[threadIdx.x] = s[threadIdx.x] - v;
}

__global__ __launch_bounds__(SCAN_B) void scan3_kernel(
    int* __restrict__ starts, const int* __restrict__ blockSums,
    int* __restrict__ cursor) {
  int i = blockIdx.x * SCAN_B + threadIdx.x;
  if (i < N_TOT) {
    int st = starts[i] + blockSums[blockIdx.x];
    starts[i] = st;
    cursor[i] = st;
  }
}

__global__ __launch_bounds__(256) void fill_kernel(
    const int* __restrict__ src, const int* __restrict__ dst,
    const float* __restrict__ vals, int* __restrict__ cursor,
    int* __restrict__ csrSrc, float* __restrict__ csrVal) {
  int e = blockIdx.x * blockDim.x + threadIdx.x;
  if (e >= E_NUM) return;
  int d = dst[e];
  int pos = atomicAdd(&cursor[d], 1);
  csrSrc[pos] = src[e];
  csrVal[pos] = vals[e];
}

// ---------------------------------------------------------------------------
// Layer-1 pull aggregation from fp32 (CHUNKS=25). (unchanged)
// ---------------------------------------------------------------------------
template <int CHUNKS>
__global__ __launch_bounds__(256) void agg_kernel(
    const float* __restrict__ h, const int* __restrict__ starts,
    const int* __restrict__ counts, const int* __restrict__ csrSrc,
    const float* __restrict__ csrVal, float* __restrict__ out) {
  const int wave = threadIdx.x >> 6;
  const int lane = threadIdx.x & 63;
  const int row = blockIdx.x * 4 + wave;
  if (row >= N_TOT) return;
  const int st = starts[row];
  const int cnt = counts[row];
  const float4* __restrict__ h4 = reinterpret_cast<const float4*>(h);

  float4 acc = {0.f, 0.f, 0.f, 0.f};
  int j = 0;
  for (; j + 3 < cnt; j += 4) {
    int s0 = csrSrc[st + j + 0], s1 = csrSrc[st + j + 1];
    int s2 = csrSrc[st + j + 2], s3 = csrSrc[st + j + 3];
    float v0 = csrVal[st + j + 0], v1 = csrVal[st + j + 1];
    float v2 = csrVal[st + j + 2], v3 = csrVal[st + j + 3];
    if (lane < CHUNKS) {
      float4 a = h4[(long)s0 * CHUNKS + lane];
      float4 b = h4[(long)s1 * CHUNKS + lane];
      float4 c = h4[(long)s2 * CHUNKS + lane];
      float4 d = h4[(long)s3 * CHUNKS + lane];
      acc.x += a.x * v0 + b.x * v1 + c.x * v2 + d.x * v3;
      acc.y += a.y * v0 + b.y * v1 + c.y * v2 + d.y * v3;
      acc.z += a.z * v0 + b.z * v1 + c.z * v2 + d.z * v3;
      acc.w += a.w * v0 + b.w * v1 + c.w * v2 + d.w * v3;
    }
  }
  for (; j < cnt; ++j) {
    int s0 = csrSrc[st + j];
    float v0 = csrVal[st + j];
    if (lane < CHUNKS) {
      float4 a = h4[(long)s0 * CHUNKS + lane];
      acc.x += a.x * v0;
      acc.y += a.y * v0;
      acc.z += a.z * v0;
      acc.w += a.w * v0;
    }
  }
  if (lane < CHUNKS)
    reinterpret_cast<float4*>(out)[(long)row * CHUNKS + lane] = acc;
}

// ---------------------------------------------------------------------------
// Layer-2 pull aggregation from bf16 h1 -> bf16 g2b [N][KP] (zero K-pad).
// ---------------------------------------------------------------------------
__global__ __launch_bounds__(256) void agg2_bf16_kernel(
    const unsigned short* __restrict__ h, const int* __restrict__ starts,
    const int* __restrict__ counts, const int* __restrict__ csrSrc,
    const float* __restrict__ csrVal, unsigned short* __restrict__ out) {
  const int wave = threadIdx.x >> 6;
  const int lane = threadIdx.x & 63;
  const int row = blockIdx.x * 4 + wave;
  if (row >= N_TOT) return;
  const int st = starts[row];
  const int cnt = counts[row];
  const ushort4* __restrict__ h4 = reinterpret_cast<const ushort4*>(h);

  float4 acc = {0.f, 0.f, 0.f, 0.f};
  int j = 0;
  for (; j + 3 < cnt; j += 4) {
    int s0 = csrSrc[st + j + 0], s1 = csrSrc[st + j + 1];
    int s2 = csrSrc[st + j + 2], s3 = csrSrc[st + j + 3];
    float v0 = csrVal[st + j + 0], v1 = csrVal[st + j + 1];
    float v2 = csrVal[st + j + 2], v3 = csrVal[st + j + 3];
    if (lane < 50) {
      ushort4 a = h4[(long)s0 * 50 + lane];
      ushort4 b = h4[(long)s1 * 50 + lane];
      ushort4 c = h4[(long)s2 * 50 + lane];
      ushort4 d = h4[(long)s3 * 50 + lane];
      acc.x += bf2f(a.x) * v0 + bf2f(b.x) * v1 + bf2f(c.x) * v2 +
               bf2f(d.x) * v3;
      acc.y += bf2f(a.y) * v0 + bf2f(b.y) * v1 + bf2f(c.y) * v2 +
               bf2f(d.y) * v3;
      acc.z += bf2f(a.z) * v0 + bf2f(b.z) * v1 + bf2f(c.z) * v2 +
               bf2f(d.z) * v3;
      acc.w += bf2f(a.w) * v0 + bf2f(b.w) * v1 + bf2f(c.w) * v2 +
               bf2f(d.w) * v3;
    }
  }
  for (; j < cnt; ++j) {
    int s0 = csrSrc[st + j];
    float v0 = csrVal[st + j];
    if (lane < 50) {
      ushort4 a = h4[(long)s0 * 50 + lane];
      acc.x += bf2f(a.x) * v0;
      acc.y += bf2f(a.y) * v0;
      acc.z += bf2f(a.z) * v0;
      acc.w += bf2f(a.w) * v0;
    }
  }
  // row stride KP=224 bf16 = 56 ushort4; lanes 50..55 zero the K-pad.
  if (lane < 50) {
    ushort4 ob = {f2bf(acc.x), f2bf(acc.y), f2bf(acc.z), f2bf(acc.w)};
    reinterpret_cast<ushort4*>(out)[(long)row * 56 + lane] = ob;
  } else if (lane < 56) {
    ushort4 z = {0, 0, 0, 0};
    reinterpret_cast<ushort4*>(out)[(long)row * 56 + lane] = z;
  }
}

// ---------------------------------------------------------------------------
extern "C" void kernel_launch(void* const* d_in, const int* in_sizes, int n_in,
                              void* d_out, int out_size, void* d_ws,
                              size_t ws_size, hipStream_t stream) {
  const float* emb = (const float*)d_in[0];   // [N_TOT, 100]
  const float* W1 = (const float*)d_in[1];    // [100, 200]
  const float* W2 = (const float*)d_in[2];    // [200, 200]
  const int* eidx = (const int*)d_in[3];      // [2, E]
  const float* vals = (const float*)d_in[4];  // [E]
  const int* src = eidx;
  const int* dst = eidx + E_NUM;
  float* out = (float*)d_out;                 // [N_TOT, 200] fp32

  // h1 (bf16, 20.2 MB) in the front half of d_out; dead before gemm2 writes.
  unsigned short* h1b = (unsigned short*)d_out;

  // ---- workspace layout (~50 MB) ----
  char* p = (char*)d_ws;
  auto take = [&](size_t bytes) {
    char* r = p;
    p += (bytes + 255) & ~(size_t)255;
    return r;
  };
  float* g1 = (float*)take((size_t)N_TOT * D_IN_ * sizeof(float));
  unsigned short* g2b =
      (unsigned short*)take((size_t)N_TOT * KP * sizeof(unsigned short));
  unsigned short* w2t =
      (unsigned short*)take((size_t)CF * 16 * KP * sizeof(unsigned short));
  int* csrSrc = (int*)take((size_t)E_NUM * sizeof(int));
  float* csrVal = (float*)take((size_t)E_NUM * sizeof(float));
  int* counts = (int*)take((size_t)N_TOT * sizeof(int));
  int* starts = (int*)take((size_t)N_TOT * sizeof(int));
  int* cursor = (int*)take((size_t)N_TOT * sizeof(int));
  int* blockSums = (int*)take((size_t)NBLK_SCAN * sizeof(int));

  const int eBlocks = (E_NUM + 255) / 256;
  const int rowWaveBlocks = (N_TOT + 3) / 4;

  // ---- CSR build + W2 transpose (shared / once) ----
  hipMemsetAsync(counts, 0, (size_t)N_TOT * sizeof(int), stream);
  hist_kernel<<<eBlocks, 256, 0, stream>>>(dst, counts);
  scan1_kernel<<<NBLK_SCAN, SCAN_B, 0, stream>>>(counts, starts, blockSums);
  scan2_kernel<<<1, SCAN_B, 0, stream>>>(blockSums);
  scan3_kernel<<<NBLK_SCAN, SCAN_B, 0, stream>>>(starts, blockSums, cursor);
  fill_kernel<<<eBlocks, 256, 0, stream>>>(src, dst, vals, cursor, csrSrc,
                                           csrVal);
  w2t_kernel<<<(CF * 16 * KP + 255) / 256, 256, 0, stream>>>(W2, w2t);

  const int gemmBlocks = 8 * ((N_PANELS + 7) / 8) * 4;  // 1600 (layer 1)

  // ---- layer 1: agg emb (100-dim) -> fp32 gemm (+lrelu) -> bf16 h1 ----
  agg_kernel<25><<<rowWaveBlocks, 256, 0, stream>>>(emb, starts, counts,
                                                    csrSrc, csrVal, g1);
  gemm_kernel<true, true><<<gemmBlocks, 256, 0, stream>>>(
      g1, W1, (void*)h1b, N_TOT, D_IN_, D_HID);

  // ---- layer 2: bf16 gather-agg -> MFMA gemm + fused lrelu+normalize ----
  agg2_bf16_kernel<<<rowWaveBlocks, 256, 0, stream>>>(h1b, starts, counts,
                                                      csrSrc, csrVal, g2b);
  gemm2_mfma_kernel<<<(N_TOT + BROW - 1) / BROW, 256, 0, stream>>>(g2b, w2t,
                                                                   out);
}

// Round 16
// 335.811 us; speedup vs baseline: 1.4566x; 1.1150x over previous
//
#include <hip/hip_runtime.h>

#define N_TOT 50500
#define E_NUM 800000
#define D_IN_ 100
#define D_HID 200
#define ALPHA 0.2f
#define EPS_ 1e-12f
#define SCAN_B 256
#define NBLK_SCAN ((N_TOT + SCAN_B - 1) / SCAN_B)  // 198

// MFMA geometry (shared by both layers)
#define KP1 128  // layer-1 K: 100 padded to 4x32
#define KP 224   // layer-2 K: 200 padded to 7x32
#define CF 13    // col fragments: 13*16 = 208 >= 200
#define BROW 64  // rows per block (4 waves x 16)
#define LDK 40   // LDS k-stride in bf16 (32 + 8 pad)

typedef __attribute__((ext_vector_type(8))) short short8x;  // 8 bf16
typedef __attribute__((ext_vector_type(4))) float f32x4;

// ---- fp32 <-> bf16 helpers (RNE pack; shift-only unpack) ----
__device__ __forceinline__ unsigned short f2bf(float f) {
  unsigned u = __float_as_uint(f);
  u += 0x7FFFu + ((u >> 16) & 1u);
  return (unsigned short)(u >> 16);
}
__device__ __forceinline__ float bf2f(unsigned short s) {
  return __uint_as_float(((unsigned)s) << 16);
}

// ---------------------------------------------------------------------------
// Weight transposes to bf16, zero-padded: W[k][c] -> BT[c][k].
// ---------------------------------------------------------------------------
__global__ __launch_bounds__(256) void w1t_kernel(
    const float* __restrict__ W1, unsigned short* __restrict__ BT) {
  int idx = blockIdx.x * 256 + threadIdx.x;
  if (idx >= CF * 16 * KP1) return;
  int c = idx / KP1, k = idx % KP1;
  float v = (c < D_HID && k < D_IN_) ? W1[(long)k * D_HID + c] : 0.f;
  BT[idx] = f2bf(v);
}

__global__ __launch_bounds__(256) void w2t_kernel(
    const float* __restrict__ W2, unsigned short* __restrict__ BT) {
  int idx = blockIdx.x * 256 + threadIdx.x;
  if (idx >= CF * 16 * KP) return;
  int c = idx / KP, k = idx % KP;
  float v = (c < D_HID && k < D_HID) ? W2[(long)k * D_HID + c] : 0.f;
  BT[idx] = f2bf(v);
}

// ---------------------------------------------------------------------------
// Layer-1 MFMA GEMM + lrelu -> bf16 h1. h1b[N][200] = lrelu(g1b @ W1T^T).
// 64 rows/block, 4 waves x 16 rows, 13 col-frags of mfma_f32_16x16x32_bf16.
// C/D layout (m89): col = lane&15, row = (lane>>4)*4 + i.
// ---------------------------------------------------------------------------
__global__ __launch_bounds__(256) void gemm1_mfma_kernel(
    const unsigned short* __restrict__ A,   // g1b [N][KP1] bf16
    const unsigned short* __restrict__ BT,  // w1t [208][KP1] bf16
    unsigned short* __restrict__ C) {       // h1b [N][200] bf16
  __shared__ __align__(16) short A_lds[BROW * LDK];
  __shared__ __align__(16) short B_lds[CF * 16 * LDK];
  const int tid = threadIdx.x;
  const int wave = tid >> 6;
  const int lane = tid & 63;
  const int l15 = lane & 15;
  const int lg = lane >> 4;
  const int rowBase = blockIdx.x * BROW;
  const int wRow = rowBase + wave * 16;

  f32x4 acc[CF] = {};

  for (int k0 = 0; k0 < KP1; k0 += 32) {
    {
      int r = tid >> 2;
      int koff = (tid & 3) * 8;
      int gr = rowBase + r;
      short8x v = {};
      if (gr < N_TOT)
        v = *reinterpret_cast<const short8x*>(A + (long)gr * KP1 + k0 + koff);
      *reinterpret_cast<short8x*>(&A_lds[r * LDK + koff]) = v;
    }
    for (int idx = tid; idx < CF * 16 * 4; idx += 256) {
      int col = idx >> 2;
      int koff = (idx & 3) * 8;
      short8x v =
          *reinterpret_cast<const short8x*>(BT + (long)col * KP1 + k0 + koff);
      *reinterpret_cast<short8x*>(&B_lds[col * LDK + koff]) = v;
    }
    __syncthreads();

    short8x a = *reinterpret_cast<const short8x*>(
        &A_lds[(wave * 16 + l15) * LDK + lg * 8]);
#pragma unroll
    for (int cf = 0; cf < CF; ++cf) {
      short8x b = *reinterpret_cast<const short8x*>(
          &B_lds[(cf * 16 + l15) * LDK + lg * 8]);
      acc[cf] = __builtin_amdgcn_mfma_f32_16x16x32_bf16(a, b, acc[cf], 0, 0, 0);
    }
    __syncthreads();
  }

  if (wRow >= N_TOT) return;

#pragma unroll
  for (int cf = 0; cf < CF; ++cf) {
    int col = cf * 16 + l15;
    if (col < D_HID) {
#pragma unroll
      for (int i = 0; i < 4; ++i) {
        int gr = wRow + lg * 4 + i;
        if (gr < N_TOT) {
          float v = acc[cf][i];
          v = v > 0.f ? v : ALPHA * v;
          C[(long)gr * D_HID + col] = f2bf(v);
        }
      }
    }
  }
}

// ---------------------------------------------------------------------------
// Layer-2 MFMA GEMM + fused lrelu + L2 row-normalize -> fp32 d_out.
// (unchanged from R14)
// ---------------------------------------------------------------------------
__global__ __launch_bounds__(256) void gemm2_mfma_kernel(
    const unsigned short* __restrict__ A,   // g2b [N][KP] bf16
    const unsigned short* __restrict__ BT,  // w2t [208][KP] bf16
    float* __restrict__ C) {                // d_out [N][200] fp32
  __shared__ __align__(16) short A_lds[BROW * LDK];
  __shared__ __align__(16) short B_lds[CF * 16 * LDK];
  const int tid = threadIdx.x;
  const int wave = tid >> 6;
  const int lane = tid & 63;
  const int l15 = lane & 15;
  const int lg = lane >> 4;
  const int rowBase = blockIdx.x * BROW;
  const int wRow = rowBase + wave * 16;

  f32x4 acc[CF] = {};

  for (int k0 = 0; k0 < KP; k0 += 32) {
    {
      int r = tid >> 2;
      int koff = (tid & 3) * 8;
      int gr = rowBase + r;
      short8x v = {};
      if (gr < N_TOT)
        v = *reinterpret_cast<const short8x*>(A + (long)gr * KP + k0 + koff);
      *reinterpret_cast<short8x*>(&A_lds[r * LDK + koff]) = v;
    }
    for (int idx = tid; idx < CF * 16 * 4; idx += 256) {
      int col = idx >> 2;
      int koff = (idx & 3) * 8;
      short8x v =
          *reinterpret_cast<const short8x*>(BT + (long)col * KP + k0 + koff);
      *reinterpret_cast<short8x*>(&B_lds[col * LDK + koff]) = v;
    }
    __syncthreads();

    short8x a = *reinterpret_cast<const short8x*>(
        &A_lds[(wave * 16 + l15) * LDK + lg * 8]);
#pragma unroll
    for (int cf = 0; cf < CF; ++cf) {
      short8x b = *reinterpret_cast<const short8x*>(
          &B_lds[(cf * 16 + l15) * LDK + lg * 8]);
      acc[cf] = __builtin_amdgcn_mfma_f32_16x16x32_bf16(a, b, acc[cf], 0, 0, 0);
    }
    __syncthreads();
  }

  if (wRow >= N_TOT) return;

  float ss[4] = {0.f, 0.f, 0.f, 0.f};
#pragma unroll
  for (int cf = 0; cf < CF; ++cf) {
#pragma unroll
    for (int i = 0; i < 4; ++i) {
      float v = acc[cf][i];
      v = v > 0.f ? v : ALPHA * v;
      acc[cf][i] = v;
      ss[i] += v * v;  // padded cols are exact zeros
    }
  }
#pragma unroll
  for (int off = 1; off < 16; off <<= 1) {
#pragma unroll
    for (int i = 0; i < 4; ++i) ss[i] += __shfl_xor(ss[i], off);
  }
  float inv[4];
#pragma unroll
  for (int i = 0; i < 4; ++i) inv[i] = 1.f / fmaxf(sqrtf(ss[i]), EPS_);

#pragma unroll
  for (int cf = 0; cf < CF; ++cf) {
    int col = cf * 16 + l15;
    if (col < D_HID) {
#pragma unroll
      for (int i = 0; i < 4; ++i) {
        int gr = wRow + lg * 4 + i;
        if (gr < N_TOT) C[(long)gr * D_HID + col] = acc[cf][i] * inv[i];
      }
    }
  }
}

// ---------------------------------------------------------------------------
// CSR build: histogram -> 3-kernel exclusive scan -> fill. (unchanged)
// ---------------------------------------------------------------------------
__global__ __launch_bounds__(256) void hist_kernel(const int* __restrict__ dst,
                                                   int* __restrict__ counts) {
  int e = blockIdx.x * blockDim.x + threadIdx.x;
  if (e < E_NUM) atomicAdd(&counts[dst[e]], 1);
}

__global__ __launch_bounds__(SCAN_B) void scan1_kernel(
    const int* __restrict__ counts, int* __restrict__ starts,
    int* __restrict__ blockSums) {
  __shared__ int s[SCAN_B];
  int i = blockIdx.x * SCAN_B + threadIdx.x;
  int v = (i < N_TOT) ? counts[i] : 0;
  s[threadIdx.x] = v;
  __syncthreads();
  for (int off = 1; off < SCAN_B; off <<= 1) {
    int t = (threadIdx.x >= off) ? s[threadIdx.x - off] : 0;
    __syncthreads();
    s[threadIdx.x] += t;
    __syncthreads();
  }
  if (i < N_TOT) starts[i] = s[threadIdx.x] - v;
  if (threadIdx.x == SCAN_B - 1) blockSums[blockIdx.x] = s[threadIdx.x];
}

__global__ __launch_bounds__(SCAN_B) void scan2_kernel(
    int* __restrict__ blockSums) {
  __shared__ int s[SCAN_B];
  int v = (threadIdx.x < NBLK_SCAN) ? blockSums[threadIdx.x] : 0;
  s[threadIdx.x] = v;
  __syncthreads();
  for (int off = 1; off < SCAN_B; off <<= 1) {
    int t = (threadIdx.x >= off) ? s[threadIdx.x - off] : 0;
    __syncthreads();
    s[threadIdx.x] += t;
    __syncthreads();
  }
  if (threadIdx.x < NBLK_SCAN) blockSums[threadIdx.x] = s[threadIdx.x] - v;
}

__global__ __launch_bounds__(SCAN_B) void scan3_kernel(
    int* __restrict__ starts, const int* __restrict__ blockSums,
    int* __restrict__ cursor) {
  int i = blockIdx.x * SCAN_B + threadIdx.x;
  if (i < N_TOT) {
    int st = starts[i] + blockSums[blockIdx.x];
    starts[i] = st;
    cursor[i] = st;
  }
}

__global__ __launch_bounds__(256) void fill_kernel(
    const int* __restrict__ src, const int* __restrict__ dst,
    const float* __restrict__ vals, int* __restrict__ cursor,
    int* __restrict__ csrSrc, float* __restrict__ csrVal) {
  int e = blockIdx.x * blockDim.x + threadIdx.x;
  if (e >= E_NUM) return;
  int d = dst[e];
  int pos = atomicAdd(&cursor[d], 1);
  csrSrc[pos] = src[e];
  csrVal[pos] = vals[e];
}

// ---------------------------------------------------------------------------
// Layer-1 pull aggregation: gather fp32 emb -> bf16 g1b [N][KP1=128].
// Lanes 0..24 own one float4 (100 floats); pack to ushort4; lanes 25..31
// zero the K-pad. Row stride = 128 bf16 = 32 ushort4.
// ---------------------------------------------------------------------------
__global__ __launch_bounds__(256) void agg1_bf16_kernel(
    const float* __restrict__ h, const int* __restrict__ starts,
    const int* __restrict__ counts, const int* __restrict__ csrSrc,
    const float* __restrict__ csrVal, unsigned short* __restrict__ out) {
  const int wave = threadIdx.x >> 6;
  const int lane = threadIdx.x & 63;
  const int row = blockIdx.x * 4 + wave;
  if (row >= N_TOT) return;
  const int st = starts[row];
  const int cnt = counts[row];
  const float4* __restrict__ h4 = reinterpret_cast<const float4*>(h);

  float4 acc = {0.f, 0.f, 0.f, 0.f};
  int j = 0;
  for (; j + 3 < cnt; j += 4) {
    int s0 = csrSrc[st + j + 0], s1 = csrSrc[st + j + 1];
    int s2 = csrSrc[st + j + 2], s3 = csrSrc[st + j + 3];
    float v0 = csrVal[st + j + 0], v1 = csrVal[st + j + 1];
    float v2 = csrVal[st + j + 2], v3 = csrVal[st + j + 3];
    if (lane < 25) {
      float4 a = h4[(long)s0 * 25 + lane];
      float4 b = h4[(long)s1 * 25 + lane];
      float4 c = h4[(long)s2 * 25 + lane];
      float4 d = h4[(long)s3 * 25 + lane];
      acc.x += a.x * v0 + b.x * v1 + c.x * v2 + d.x * v3;
      acc.y += a.y * v0 + b.y * v1 + c.y * v2 + d.y * v3;
      acc.z += a.z * v0 + b.z * v1 + c.z * v2 + d.z * v3;
      acc.w += a.w * v0 + b.w * v1 + c.w * v2 + d.w * v3;
    }
  }
  for (; j < cnt; ++j) {
    int s0 = csrSrc[st + j];
    float v0 = csrVal[st + j];
    if (lane < 25) {
      float4 a = h4[(long)s0 * 25 + lane];
      acc.x += a.x * v0;
      acc.y += a.y * v0;
      acc.z += a.z * v0;
      acc.w += a.w * v0;
    }
  }
  if (lane < 25) {
    ushort4 ob = {f2bf(acc.x), f2bf(acc.y), f2bf(acc.z), f2bf(acc.w)};
    reinterpret_cast<ushort4*>(out)[(long)row * 32 + lane] = ob;
  } else if (lane < 32) {
    ushort4 z = {0, 0, 0, 0};
    reinterpret_cast<ushort4*>(out)[(long)row * 32 + lane] = z;
  }
}

// ---------------------------------------------------------------------------
// Layer-2 pull aggregation: gather bf16 h1 -> bf16 g2b [N][KP=224].
// (unchanged from R14)
// ---------------------------------------------------------------------------
__global__ __launch_bounds__(256) void agg2_bf16_kernel(
    const unsigned short* __restrict__ h, const int* __restrict__ starts,
    const int* __restrict__ counts, const int* __restrict__ csrSrc,
    const float* __restrict__ csrVal, unsigned short* __restrict__ out) {
  const int wave = threadIdx.x >> 6;
  const int lane = threadIdx.x & 63;
  const int row = blockIdx.x * 4 + wave;
  if (row >= N_TOT) return;
  const int st = starts[row];
  const int cnt = counts[row];
  const ushort4* __restrict__ h4 = reinterpret_cast<const ushort4*>(h);

  float4 acc = {0.f, 0.f, 0.f, 0.f};
  int j = 0;
  for (; j + 3 < cnt; j += 4) {
    int s0 = csrSrc[st + j + 0], s1 = csrSrc[st + j + 1];
    int s2 = csrSrc[st + j + 2], s3 = csrSrc[st + j + 3];
    float v0 = csrVal[st + j + 0], v1 = csrVal[st + j + 1];
    float v2 = csrVal[st + j + 2], v3 = csrVal[st + j + 3];
    if (lane < 50) {
      ushort4 a = h4[(long)s0 * 50 + lane];
      ushort4 b = h4[(long)s1 * 50 + lane];
      ushort4 c = h4[(long)s2 * 50 + lane];
      ushort4 d = h4[(long)s3 * 50 + lane];
      acc.x += bf2f(a.x) * v0 + bf2f(b.x) * v1 + bf2f(c.x) * v2 +
               bf2f(d.x) * v3;
      acc.y += bf2f(a.y) * v0 + bf2f(b.y) * v1 + bf2f(c.y) * v2 +
               bf2f(d.y) * v3;
      acc.z += bf2f(a.z) * v0 + bf2f(b.z) * v1 + bf2f(c.z) * v2 +
               bf2f(d.z) * v3;
      acc.w += bf2f(a.w) * v0 + bf2f(b.w) * v1 + bf2f(c.w) * v2 +
               bf2f(d.w) * v3;
    }
  }
  for (; j < cnt; ++j) {
    int s0 = csrSrc[st + j];
    float v0 = csrVal[st + j];
    if (lane < 50) {
      ushort4 a = h4[(long)s0 * 50 + lane];
      acc.x += bf2f(a.x) * v0;
      acc.y += bf2f(a.y) * v0;
      acc.z += bf2f(a.z) * v0;
      acc.w += bf2f(a.w) * v0;
    }
  }
  if (lane < 50) {
    ushort4 ob = {f2bf(acc.x), f2bf(acc.y), f2bf(acc.z), f2bf(acc.w)};
    reinterpret_cast<ushort4*>(out)[(long)row * 56 + lane] = ob;
  } else if (lane < 56) {
    ushort4 z = {0, 0, 0, 0};
    reinterpret_cast<ushort4*>(out)[(long)row * 56 + lane] = z;
  }
}

// ---------------------------------------------------------------------------
extern "C" void kernel_launch(void* const* d_in, const int* in_sizes, int n_in,
                              void* d_out, int out_size, void* d_ws,
                              size_t ws_size, hipStream_t stream) {
  const float* emb = (const float*)d_in[0];   // [N_TOT, 100]
  const float* W1 = (const float*)d_in[1];    // [100, 200]
  const float* W2 = (const float*)d_in[2];    // [200, 200]
  const int* eidx = (const int*)d_in[3];      // [2, E]
  const float* vals = (const float*)d_in[4];  // [E]
  const int* src = eidx;
  const int* dst = eidx + E_NUM;
  float* out = (float*)d_out;                 // [N_TOT, 200] fp32

  // h1 (bf16, 20.2 MB) in the front half of d_out; dead before gemm2 writes.
  unsigned short* h1b = (unsigned short*)d_out;

  // ---- workspace layout (~45 MB) ----
  char* p = (char*)d_ws;
  auto take = [&](size_t bytes) {
    char* r = p;
    p += (bytes + 255) & ~(size_t)255;
    return r;
  };
  unsigned short* g1b =
      (unsigned short*)take((size_t)N_TOT * KP1 * sizeof(unsigned short));
  unsigned short* g2b =
      (unsigned short*)take((size_t)N_TOT * KP * sizeof(unsigned short));
  unsigned short* w1t =
      (unsigned short*)take((size_t)CF * 16 * KP1 * sizeof(unsigned short));
  unsigned short* w2t =
      (unsigned short*)take((size_t)CF * 16 * KP * sizeof(unsigned short));
  int* csrSrc = (int*)take((size_t)E_NUM * sizeof(int));
  float* csrVal = (float*)take((size_t)E_NUM * sizeof(float));
  int* counts = (int*)take((size_t)N_TOT * sizeof(int));
  int* starts = (int*)take((size_t)N_TOT * sizeof(int));
  int* cursor = (int*)take((size_t)N_TOT * sizeof(int));
  int* blockSums = (int*)take((size_t)NBLK_SCAN * sizeof(int));

  const int eBlocks = (E_NUM + 255) / 256;
  const int rowWaveBlocks = (N_TOT + 3) / 4;
  const int mfmaBlocks = (N_TOT + BROW - 1) / BROW;

  // ---- CSR build + weight transposes (once) ----
  hipMemsetAsync(counts, 0, (size_t)N_TOT * sizeof(int), stream);
  hist_kernel<<<eBlocks, 256, 0, stream>>>(dst, counts);
  scan1_kernel<<<NBLK_SCAN, SCAN_B, 0, stream>>>(counts, starts, blockSums);
  scan2_kernel<<<1, SCAN_B, 0, stream>>>(blockSums);
  scan3_kernel<<<NBLK_SCAN, SCAN_B, 0, stream>>>(starts, blockSums, cursor);
  fill_kernel<<<eBlocks, 256, 0, stream>>>(src, dst, vals, cursor, csrSrc,
                                           csrVal);
  w1t_kernel<<<(CF * 16 * KP1 + 255) / 256, 256, 0, stream>>>(W1, w1t);
  w2t_kernel<<<(CF * 16 * KP + 255) / 256, 256, 0, stream>>>(W2, w2t);

  // ---- layer 1: agg emb -> bf16 g1b -> MFMA gemm (+lrelu) -> bf16 h1 ----
  agg1_bf16_kernel<<<rowWaveBlocks, 256, 0, stream>>>(emb, starts, counts,
                                                      csrSrc, csrVal, g1b);
  gemm1_mfma_kernel<<<mfmaBlocks, 256, 0, stream>>>(g1b, w1t, h1b);

  // ---- layer 2: agg h1 -> bf16 g2b -> MFMA gemm + lrelu + normalize ----
  agg2_bf16_kernel<<<rowWaveBlocks, 256, 0, stream>>>(h1b, starts, counts,
                                                      csrSrc, csrVal, g2b);
  gemm2_mfma_kernel<<<mfmaBlocks, 256, 0, stream>>>(g2b, w2t, out);
}